// Round 9
// baseline (646.006 us; speedup 1.0000x reference)
//
#include <hip/hip_runtime.h>
#include <hip/hip_bf16.h>
#include <math.h>

#define F_IN 128
#define H1c 16
#define H2c 32
#define H3c 64
#define H4c 32
#define NCc 16

#define BUCKET 256
#define BSH 8
#define BMASK 255u
#define BMAXB 512        // max buckets (N <= 131072)
#define GP 512           // partition groups (grid of hist/part kernels)

typedef unsigned int u32;
typedef unsigned int u32x4 __attribute__((ext_vector_type(4)));
typedef float f32x4 __attribute__((ext_vector_type(4)));

static __device__ __forceinline__ void ldsAddU(u32* p, u32 v) {
    __hip_atomic_fetch_add(p, v, __ATOMIC_RELAXED, __HIP_MEMORY_SCOPE_WORKGROUP);
}
static __device__ __forceinline__ u32 ldsAddURtn(u32* p, u32 v) {
    return __hip_atomic_fetch_add(p, v, __ATOMIC_RELAXED, __HIP_MEMORY_SCOPE_WORKGROUP);
}
// non-temporal (evict-first) loads for streaming data
static __device__ __forceinline__ u32 ntl(const u32* p) { return __builtin_nontemporal_load(p); }
static __device__ __forceinline__ u32x4 ntl4(const u32* p) {
    return __builtin_nontemporal_load(reinterpret_cast<const u32x4*>(p));
}
static __device__ __forceinline__ float4 ntlf4(const float* p) {
    f32x4 v = __builtin_nontemporal_load(reinterpret_cast<const f32x4*>(p));
    return make_float4(v[0], v[1], v[2], v[3]);
}

// ---------------- edge dtype detect ----------------
__global__ __launch_bounds__(256) void k_detect(const u32* __restrict__ ei, u32* __restrict__ flags) {
    __shared__ int nz;
    if (threadIdx.x == 0) nz = 0;
    __syncthreads();
    for (int i = threadIdx.x; 2 * i + 1 < 8192; i += blockDim.x) {
        if (ei[2 * i + 1] != 0u) atomicAdd(&nz, 1);
    }
    __syncthreads();
    if (threadIdx.x == 0) flags[0] = (nz == 0) ? 2u : 1u;
}

// ---------------- pass A: per-group bucket histogram ----------------
__global__ __launch_bounds__(1024) void k_hist(const u32* __restrict__ ei, int E, int B,
                                               const u32* __restrict__ flags,
                                               u32* __restrict__ cntGB) {
    __shared__ u32 hist[BMAXB];
    for (int t = threadIdx.x; t < B; t += 1024) hist[t] = 0u;
    __syncthreads();
    u32 strd = flags[0];
    int chunk = (E + GP - 1) / GP;
    int e0 = blockIdx.x * chunk;
    int e1 = min(E, e0 + chunk);
    for (int e = e0 + threadIdx.x; e < e1; e += 1024) {
        u32 d = ntl(ei + ((size_t)E + (size_t)e) * strd);
        ldsAddU(&hist[d >> BSH], 1u);
    }
    __syncthreads();
    for (int t = threadIdx.x; t < B; t += 1024)
        cntGB[(size_t)blockIdx.x * B + t] = hist[t];
}

// ---------------- pass B1: per-bucket exclusive scan over groups ----------------
__global__ __launch_bounds__(GP) void k_scanG(const u32* __restrict__ cntGB, int B,
                                              u32* __restrict__ gbOff, u32* __restrict__ total) {
    __shared__ u32 s[GP];
    int b = blockIdx.x;
    u32 v = cntGB[(size_t)threadIdx.x * B + b];
    s[threadIdx.x] = v;
    __syncthreads();
    for (int o = 1; o < GP; o <<= 1) {
        u32 t = (threadIdx.x >= (u32)o) ? s[threadIdx.x - o] : 0u;
        __syncthreads();
        s[threadIdx.x] += t;
        __syncthreads();
    }
    gbOff[(size_t)threadIdx.x * B + b] = s[threadIdx.x] - v;
    if (threadIdx.x == GP - 1) total[b] = s[GP - 1];
}

// ---------------- pass B2: bucket starts, padded to 4-entry alignment ----------------
__global__ __launch_bounds__(256) void k_scanB(const u32* __restrict__ total, int B,
                                               u32* __restrict__ bstartP) {
    __shared__ u32 s[256];
    int per = (B + 255) / 256;
    int i0 = threadIdx.x * per;
    int iend = min(B, i0 + per);
    u32 sum = 0u;
    for (int i = i0; i < iend; ++i) sum += (total[i] + 3u) & ~3u;
    s[threadIdx.x] = sum;
    __syncthreads();
    for (int o = 1; o < 256; o <<= 1) {
        u32 t = (threadIdx.x >= (u32)o) ? s[threadIdx.x - o] : 0u;
        __syncthreads();
        s[threadIdx.x] += t;
        __syncthreads();
    }
    u32 run = s[threadIdx.x] - sum;  // exclusive prefix
    for (int i = i0; i < iend; ++i) { bstartP[i] = run; run += (total[i] + 3u) & ~3u; }
}

// ---------------- pass C: partition edges, entry = (src<<8)|dst_local ----------------
__global__ __launch_bounds__(1024) void k_part(const u32* __restrict__ ei, int E, int B,
                                               const u32* __restrict__ flags,
                                               const u32* __restrict__ gbOff,
                                               const u32* __restrict__ bstartP,
                                               u32* __restrict__ bbuf) {
    __shared__ u32 cur[BMAXB];
    for (int t = threadIdx.x; t < B; t += 1024)
        cur[t] = bstartP[t] + gbOff[(size_t)blockIdx.x * B + t];
    __syncthreads();
    u32 strd = flags[0];
    int chunk = (E + GP - 1) / GP;
    int e0 = blockIdx.x * chunk;
    int e1 = min(E, e0 + chunk);
    for (int e = e0 + threadIdx.x; e < e1; e += 1024) {
        u32 sidx = ntl(ei + (size_t)e * strd);
        u32 d = ntl(ei + ((size_t)E + (size_t)e) * strd);
        u32 p = atomicAdd(&cur[d >> BSH], 1u);
        bbuf[p] = (sidx << BSH) | (d & BMASK);
    }
}

// ---------------- pass D: per-bucket CSR finalize (256-node window, 1024 thr) ----------------
__global__ __launch_bounds__(1024) void k_csr(const u32* __restrict__ bbuf,
                                              const u32* __restrict__ bstartP,
                                              const u32* __restrict__ total, int N,
                                              u32* __restrict__ cnt, u32* __restrict__ off,
                                              float* __restrict__ dinv, u32* __restrict__ perm) {
    __shared__ u32 ncnt[BUCKET];
    __shared__ u32 sc[BUCKET];
    __shared__ u32 ncur[BUCKET];
    int b = blockIdx.x;
    u32 base = bstartP[b], tot = total[b];
    if (threadIdx.x < BUCKET) ncnt[threadIdx.x] = 0u;
    __syncthreads();
    u32 nv4 = tot >> 2;
    for (u32 q = threadIdx.x; q < nv4; q += 1024) {
        u32x4 e4 = ntl4(bbuf + base + q * 4);
        ldsAddU(&ncnt[e4[0] & BMASK], 1u);
        ldsAddU(&ncnt[e4[1] & BMASK], 1u);
        ldsAddU(&ncnt[e4[2] & BMASK], 1u);
        ldsAddU(&ncnt[e4[3] & BMASK], 1u);
    }
    u32 i0 = (nv4 << 2) + threadIdx.x;
    if (i0 < tot) ldsAddU(&ncnt[bbuf[base + i0] & BMASK], 1u);
    __syncthreads();
    u32 v = 0u;
    if (threadIdx.x < BUCKET) { v = ncnt[threadIdx.x]; sc[threadIdx.x] = v; }
    __syncthreads();
    for (int o = 1; o < BUCKET; o <<= 1) {
        u32 t = 0u;
        if (threadIdx.x < BUCKET && threadIdx.x >= (u32)o) t = sc[threadIdx.x - o];
        __syncthreads();
        if (threadIdx.x < BUCKET) sc[threadIdx.x] += t;
        __syncthreads();
    }
    if (threadIdx.x < BUCKET) {
        u32 o = base + (sc[threadIdx.x] - v);    // exclusive
        ncur[threadIdx.x] = o;
        int node = b * BUCKET + (int)threadIdx.x;
        if (node < N) {
            cnt[node] = v;
            off[node] = o;
            dinv[node] = rsqrtf((float)(v + 1u));  // +1 self-loop
        }
    }
    __syncthreads();
    for (u32 q = threadIdx.x; q < nv4; q += 1024) {
        u32x4 e4 = ntl4(bbuf + base + q * 4);
        u32 p;
        p = ldsAddURtn(&ncur[e4[0] & BMASK], 1u); perm[p] = e4[0] >> BSH;
        p = ldsAddURtn(&ncur[e4[1] & BMASK], 1u); perm[p] = e4[1] >> BSH;
        p = ldsAddURtn(&ncur[e4[2] & BMASK], 1u); perm[p] = e4[2] >> BSH;
        p = ldsAddURtn(&ncur[e4[3] & BMASK], 1u); perm[p] = e4[3] >> BSH;
    }
    if (i0 < tot) {
        u32 e = bbuf[base + i0];
        u32 p = ldsAddURtn(&ncur[e & BMASK], 1u);
        perm[p] = e >> BSH;
    }
}

// ---------------- h1sp[c>>3][r][c&7] = (x[r,:] @ W1)[c] * dinv[r] (2 planes) ----------------
__global__ __launch_bounds__(256) void k_xw1(const float* __restrict__ x, const float* __restrict__ W1,
                                             const float* __restrict__ dinv, float* __restrict__ h1s, int n) {
    __shared__ float Ws[F_IN * H1c];  // 8 KB
    for (int t = threadIdx.x; t < F_IN * H1c; t += 256) Ws[t] = W1[t];
    __syncthreads();
    int r = blockIdx.x * 16 + (threadIdx.x >> 4);
    int c = threadIdx.x & 15;
    if (r >= n) return;
    const float* xr = x + (size_t)r * F_IN;
    float a0 = 0.f, a1 = 0.f;
    #pragma unroll
    for (int k = 0; k < F_IN; k += 4) {
        float4 xv = ntlf4(xr + k);
        a0 += xv.x * Ws[(k + 0) * H1c + c];
        a1 += xv.y * Ws[(k + 1) * H1c + c];
        a0 += xv.z * Ws[(k + 2) * H1c + c];
        a1 += xv.w * Ws[(k + 3) * H1c + c];
    }
    h1s[(size_t)(c >> 3) * n * 8 + (size_t)r * 8 + (c & 7)] = (a0 + a1) * dinv[r];
}

// ---------------- GCN1 aggregate: 2 planes x [N][8], 2 lanes/node ----------------
// p2p[plane][node] = relu(dinv*(sum + self) + b1) * dinv
__global__ __launch_bounds__(256) void k_agg1(const float* __restrict__ h1s, const u32* __restrict__ perm,
                                              const u32* __restrict__ off, const u32* __restrict__ cnt,
                                              const float* __restrict__ dinv, const float* __restrict__ b1,
                                              float* __restrict__ p2, int N) {
    int plane = blockIdx.x & 1;
    int nb = blockIdx.x >> 1;
    int g = threadIdx.x >> 1, l = threadIdx.x & 1;
    int node = nb * 128 + g;
    if (node >= N) return;
    const float* hp = h1s + (size_t)plane * N * 8;
    u32 s0 = off[node], len = cnt[node];
    int fo = l * 4;
    float x0 = 0.f, y0 = 0.f, z0 = 0.f, w0 = 0.f;
    float x1 = 0.f, y1 = 0.f, z1 = 0.f, w1 = 0.f;
    float x2 = 0.f, y2 = 0.f, z2 = 0.f, w2 = 0.f;
    float x3 = 0.f, y3 = 0.f, z3 = 0.f, w3 = 0.f;
    u32 it = 0;
    for (; it + 4 <= len; it += 4) {
        u32 e0 = ntl(perm + s0 + it),     e1 = ntl(perm + s0 + it + 1);
        u32 e2 = ntl(perm + s0 + it + 2), e3 = ntl(perm + s0 + it + 3);
        float4 v0 = *reinterpret_cast<const float4*>(hp + (size_t)e0 * 8 + fo);
        float4 v1 = *reinterpret_cast<const float4*>(hp + (size_t)e1 * 8 + fo);
        float4 v2 = *reinterpret_cast<const float4*>(hp + (size_t)e2 * 8 + fo);
        float4 v3 = *reinterpret_cast<const float4*>(hp + (size_t)e3 * 8 + fo);
        x0 += v0.x; y0 += v0.y; z0 += v0.z; w0 += v0.w;
        x1 += v1.x; y1 += v1.y; z1 += v1.z; w1 += v1.w;
        x2 += v2.x; y2 += v2.y; z2 += v2.z; w2 += v2.w;
        x3 += v3.x; y3 += v3.y; z3 += v3.z; w3 += v3.w;
    }
    for (; it < len; ++it) {
        u32 e = ntl(perm + s0 + it);
        float4 v = *reinterpret_cast<const float4*>(hp + (size_t)e * 8 + fo);
        x0 += v.x; y0 += v.y; z0 += v.z; w0 += v.w;
    }
    float4 self = *reinterpret_cast<const float4*>(hp + (size_t)node * 8 + fo);
    float dv = dinv[node];
    float4 bv = *reinterpret_cast<const float4*>(b1 + plane * 8 + fo);
    float4 r;
    r.x = fmaxf(dv * ((x0 + x1) + (x2 + x3) + self.x) + bv.x, 0.f) * dv;
    r.y = fmaxf(dv * ((y0 + y1) + (y2 + y3) + self.y) + bv.y, 0.f) * dv;
    r.z = fmaxf(dv * ((z0 + z1) + (z2 + z3) + self.z) + bv.z, 0.f) * dv;
    r.w = fmaxf(dv * ((w0 + w1) + (w2 + w3) + self.w) + bv.w, 0.f) * dv;
    *reinterpret_cast<float4*>(p2 + (size_t)plane * N * 8 + (size_t)node * 8 + fo) = r;
}

// ---------------- GCN2 aggregate: 2 planes x [N][8] -> g2 (pre-W2) ----------------
__global__ __launch_bounds__(256) void k_agg2(const float* __restrict__ p2, const u32* __restrict__ perm,
                                              const u32* __restrict__ off, const u32* __restrict__ cnt,
                                              const float* __restrict__ dinv,
                                              float* __restrict__ g2, int N) {
    int plane = blockIdx.x & 1;
    int nb = blockIdx.x >> 1;
    int g = threadIdx.x >> 1, l = threadIdx.x & 1;
    int node = nb * 128 + g;
    if (node >= N) return;
    const float* hp = p2 + (size_t)plane * N * 8;
    u32 s0 = off[node], len = cnt[node];
    int fo = l * 4;
    float x0 = 0.f, y0 = 0.f, z0 = 0.f, w0 = 0.f;
    float x1 = 0.f, y1 = 0.f, z1 = 0.f, w1 = 0.f;
    float x2 = 0.f, y2 = 0.f, z2 = 0.f, w2 = 0.f;
    float x3 = 0.f, y3 = 0.f, z3 = 0.f, w3 = 0.f;
    u32 it = 0;
    for (; it + 4 <= len; it += 4) {
        u32 e0 = ntl(perm + s0 + it),     e1 = ntl(perm + s0 + it + 1);
        u32 e2 = ntl(perm + s0 + it + 2), e3 = ntl(perm + s0 + it + 3);
        float4 v0 = *reinterpret_cast<const float4*>(hp + (size_t)e0 * 8 + fo);
        float4 v1 = *reinterpret_cast<const float4*>(hp + (size_t)e1 * 8 + fo);
        float4 v2 = *reinterpret_cast<const float4*>(hp + (size_t)e2 * 8 + fo);
        float4 v3 = *reinterpret_cast<const float4*>(hp + (size_t)e3 * 8 + fo);
        x0 += v0.x; y0 += v0.y; z0 += v0.z; w0 += v0.w;
        x1 += v1.x; y1 += v1.y; z1 += v1.z; w1 += v1.w;
        x2 += v2.x; y2 += v2.y; z2 += v2.z; w2 += v2.w;
        x3 += v3.x; y3 += v3.y; z3 += v3.z; w3 += v3.w;
    }
    for (; it < len; ++it) {
        u32 e = ntl(perm + s0 + it);
        float4 v = *reinterpret_cast<const float4*>(hp + (size_t)e * 8 + fo);
        x0 += v.x; y0 += v.y; z0 += v.z; w0 += v.w;
    }
    float4 self = *reinterpret_cast<const float4*>(hp + (size_t)node * 8 + fo);
    float dv = dinv[node];
    float4 r;
    r.x = dv * ((x0 + x1) + (x2 + x3) + self.x);
    r.y = dv * ((y0 + y1) + (y2 + y3) + self.y);
    r.z = dv * ((z0 + z1) + (z2 + z3) + self.z);
    r.w = dv * ((w0 + w1) + (w2 + w3) + self.w);
    *reinterpret_cast<float4*>(g2 + (size_t)plane * N * 8 + (size_t)node * 8 + fo) = r;
}

// ---------------- h2post = relu(g2 @ W2 + b2)  (one thread per node) ----------------
__global__ __launch_bounds__(256) void k_h2w2(const float* __restrict__ g2,
                                              const float* __restrict__ W2, const float* __restrict__ b2,
                                              float* __restrict__ h2post, int N) {
    __shared__ float W2s[H1c * H2c];
    __shared__ float b2s[H2c];
    for (int t = threadIdx.x; t < H1c * H2c; t += 256) W2s[t] = W2[t];
    if (threadIdx.x < H2c) b2s[threadIdx.x] = b2[threadIdx.x];
    __syncthreads();
    int r = blockIdx.x * 256 + threadIdx.x;
    if (r >= N) return;
    float h[H1c];
    float4 a = ntlf4(g2 + (size_t)r * 8);
    float4 b = ntlf4(g2 + (size_t)r * 8 + 4);
    float4 c = ntlf4(g2 + (size_t)N * 8 + (size_t)r * 8);
    float4 d = ntlf4(g2 + (size_t)N * 8 + (size_t)r * 8 + 4);
    h[0] = a.x; h[1] = a.y; h[2] = a.z; h[3] = a.w;
    h[4] = b.x; h[5] = b.y; h[6] = b.z; h[7] = b.w;
    h[8] = c.x; h[9] = c.y; h[10] = c.z; h[11] = c.w;
    h[12] = d.x; h[13] = d.y; h[14] = d.z; h[15] = d.w;
    #pragma unroll
    for (int c0 = 0; c0 < H2c; c0 += 4) {
        float o0 = b2s[c0], o1 = b2s[c0 + 1], o2 = b2s[c0 + 2], o3 = b2s[c0 + 3];
        #pragma unroll
        for (int k = 0; k < H1c; ++k) {
            float hv = h[k];
            o0 += hv * W2s[k * H2c + c0];
            o1 += hv * W2s[k * H2c + c0 + 1];
            o2 += hv * W2s[k * H2c + c0 + 2];
            o3 += hv * W2s[k * H2c + c0 + 3];
        }
        *reinterpret_cast<float4*>(h2post + (size_t)r * H2c + c0) =
            make_float4(fmaxf(o0, 0.f), fmaxf(o1, 0.f), fmaxf(o2, 0.f), fmaxf(o3, 0.f));
    }
}

// ---------------- fused MLP (plain [N][32] h2post) ----------------
__global__ __launch_bounds__(256) void k_mlp(const float* __restrict__ h2post,
                                             const float* __restrict__ Wf1, const float* __restrict__ bf1,
                                             const float* __restrict__ Wf2, const float* __restrict__ bf2,
                                             const float* __restrict__ Wf3, const float* __restrict__ bf3,
                                             float* __restrict__ out, int n) {
    __shared__ float W1s[H2c * H3c];
    __shared__ float W2s[H3c * H4c];
    __shared__ float W3s[H4c * NCc];
    __shared__ float b1s[H3c], b2s[H4c], b3s[NCc];
    for (int t = threadIdx.x; t < H2c * H3c; t += 256) W1s[t] = Wf1[t];
    for (int t = threadIdx.x; t < H3c * H4c; t += 256) W2s[t] = Wf2[t];
    for (int t = threadIdx.x; t < H4c * NCc; t += 256) W3s[t] = Wf3[t];
    if (threadIdx.x < H3c) b1s[threadIdx.x] = bf1[threadIdx.x];
    if (threadIdx.x < H4c) b2s[threadIdx.x] = bf2[threadIdx.x];
    if (threadIdx.x < NCc) b3s[threadIdx.x] = bf3[threadIdx.x];
    __syncthreads();

    int r = blockIdx.x * 256 + threadIdx.x;
    if (r >= n) return;

    float h2v[H2c];
    #pragma unroll
    for (int k = 0; k < H2c; k += 4) {
        float4 v = ntlf4(h2post + (size_t)r * H2c + k);
        h2v[k] = v.x; h2v[k + 1] = v.y; h2v[k + 2] = v.z; h2v[k + 3] = v.w;
    }
    float a4[H4c];
    #pragma unroll
    for (int k2 = 0; k2 < H4c; ++k2) a4[k2] = b2s[k2];
    #pragma unroll 4
    for (int j = 0; j < H3c; ++j) {
        float t = b1s[j];
        #pragma unroll
        for (int k = 0; k < H2c; ++k) t += h2v[k] * W1s[k * H3c + j];
        t = fmaxf(t, 0.f);
        #pragma unroll
        for (int k2 = 0; k2 < H4c; ++k2) a4[k2] += t * W2s[j * H4c + k2];
    }
    #pragma unroll
    for (int k2 = 0; k2 < H4c; ++k2) a4[k2] = fmaxf(a4[k2], 0.f);

    #pragma unroll
    for (int c0 = 0; c0 < NCc; c0 += 4) {
        float o0 = b3s[c0], o1 = b3s[c0 + 1], o2 = b3s[c0 + 2], o3 = b3s[c0 + 3];
        #pragma unroll
        for (int k2 = 0; k2 < H4c; ++k2) {
            float a = a4[k2];
            o0 += a * W3s[k2 * NCc + c0];
            o1 += a * W3s[k2 * NCc + c0 + 1];
            o2 += a * W3s[k2 * NCc + c0 + 2];
            o3 += a * W3s[k2 * NCc + c0 + 3];
        }
        *reinterpret_cast<float4*>(out + (size_t)r * NCc + c0) = make_float4(o0, o1, o2, o3);
    }
}

extern "C" void kernel_launch(void* const* d_in, const int* in_sizes, int n_in,
                              void* d_out, int out_size, void* d_ws, size_t ws_size,
                              hipStream_t stream) {
    const float* x   = (const float*)d_in[0];
    const float* W1  = (const float*)d_in[1];
    const float* b1  = (const float*)d_in[2];
    const float* W2  = (const float*)d_in[3];
    const float* b2  = (const float*)d_in[4];
    const float* Wf1 = (const float*)d_in[5];
    const float* bf1 = (const float*)d_in[6];
    const float* Wf2 = (const float*)d_in[7];
    const float* bf2 = (const float*)d_in[8];
    const float* Wf3 = (const float*)d_in[9];
    const float* bf3 = (const float*)d_in[10];
    const u32*   ei  = (const u32*)d_in[11];

    int N = in_sizes[0] / F_IN;
    int E = in_sizes[11] / 2;
    int B = (N + BUCKET - 1) >> BSH;
    if (B > BMAXB) return;           // fixed-size problem guard

    // workspace layout (16B-aligned segments)
    char* w = (char*)d_ws;
    u32* flags  = (u32*)w;   w += 64;
    float* dinv = (float*)w; w += (size_t)((N + 3) & ~3) * 4;
    u32* cnt    = (u32*)w;   w += (size_t)((N + 3) & ~3) * 4;
    u32* off    = (u32*)w;   w += (size_t)((N + 3) & ~3) * 4;
    float* h2p  = (float*)w; w += (size_t)N * H2c * 4;      // h2post [N][32]
    u32* perm   = (u32*)w;   w += ((size_t)E + 4096) * 4;
    u32* bbuf   = (u32*)w;   w += ((size_t)E + 4096) * 4;   // dead after k_csr
    u32* cntGB  = (u32*)w;   w += (size_t)GP * BMAXB * 4;
    u32* gbOff  = (u32*)w;   w += (size_t)GP * BMAXB * 4;
    u32* total  = (u32*)w;   w += (size_t)(BMAXB + 8) * 4;
    u32* bstartP= (u32*)w;   w += (size_t)(BMAXB + 8) * 4;
    // alias bbuf (dead after k_csr): h1sp(2x[N][8]) + p2p(2x[N][8]) + g2p(2x[N][8]) = N*48 u32 <= E
    float* h1s = (float*)bbuf;                  // 2 planes x N*8
    float* p2  = h1s + (size_t)N * H1c;         // 2 planes x N*8
    float* g2  = p2  + (size_t)N * H1c;         // 2 planes x N*8

    k_detect<<<1, 256, 0, stream>>>(ei, flags);
    k_hist  <<<GP, 1024, 0, stream>>>(ei, E, B, flags, cntGB);
    k_scanG <<<B, GP, 0, stream>>>(cntGB, B, gbOff, total);
    k_scanB <<<1, 256, 0, stream>>>(total, B, bstartP);
    k_part  <<<GP, 1024, 0, stream>>>(ei, E, B, flags, gbOff, bstartP, bbuf);
    k_csr   <<<B, 1024, 0, stream>>>(bbuf, bstartP, total, N, cnt, off, dinv, perm);

    int nb16 = (N + 15) / 16;
    k_xw1<<<nb16, 256, 0, stream>>>(x, W1, dinv, h1s, N);
    int nb128 = (N + 127) / 128;
    k_agg1<<<nb128 * 2, 256, 0, stream>>>(h1s, perm, off, cnt, dinv, b1, p2, N);
    k_agg2<<<nb128 * 2, 256, 0, stream>>>(p2, perm, off, cnt, dinv, g2, N);
    int nbN = (N + 255) / 256;
    k_h2w2<<<nbN, 256, 0, stream>>>(g2, W2, b2, h2p, N);
    k_mlp<<<nbN, 256, 0, stream>>>(h2p, Wf1, bf1, Wf2, bf2, Wf3, bf3, (float*)d_out, N);
}

// Round 11
// 492.607 us; speedup vs baseline: 1.3114x; 1.3114x over previous
//
#include <hip/hip_runtime.h>
#include <hip/hip_bf16.h>
#include <math.h>

#define F_IN 128
#define H1c 16
#define H2c 32
#define H3c 64
#define H4c 32
#define NCc 16

#define BUCKET 256
#define BSH 8
#define BMASK 255u
#define BMAXB 512        // max buckets (N <= 131072)
#define GP 512           // partition groups (grid of hist/part kernels)

typedef unsigned int u32;

static __device__ __forceinline__ void ldsAddU(u32* p, u32 v) {
    __hip_atomic_fetch_add(p, v, __ATOMIC_RELAXED, __HIP_MEMORY_SCOPE_WORKGROUP);
}
static __device__ __forceinline__ u32 ldsAddURtn(u32* p, u32 v) {
    return __hip_atomic_fetch_add(p, v, __ATOMIC_RELAXED, __HIP_MEMORY_SCOPE_WORKGROUP);
}

// ---------------- edge dtype detect ----------------
__global__ __launch_bounds__(256) void k_detect(const u32* __restrict__ ei, u32* __restrict__ flags) {
    __shared__ int nz;
    if (threadIdx.x == 0) nz = 0;
    __syncthreads();
    for (int i = threadIdx.x; 2 * i + 1 < 8192; i += blockDim.x) {
        if (ei[2 * i + 1] != 0u) atomicAdd(&nz, 1);
    }
    __syncthreads();
    if (threadIdx.x == 0) flags[0] = (nz == 0) ? 2u : 1u;
}

// ---------------- pass A: per-group bucket histogram ----------------
__global__ __launch_bounds__(1024) void k_hist(const u32* __restrict__ ei, int E, int B,
                                               const u32* __restrict__ flags,
                                               u32* __restrict__ cntGB) {
    __shared__ u32 hist[BMAXB];
    for (int t = threadIdx.x; t < B; t += 1024) hist[t] = 0u;
    __syncthreads();
    u32 strd = flags[0];
    int chunk = (E + GP - 1) / GP;
    int e0 = blockIdx.x * chunk;
    int e1 = min(E, e0 + chunk);
    for (int e = e0 + threadIdx.x; e < e1; e += 1024) {
        u32 d = ei[((size_t)E + (size_t)e) * strd];
        ldsAddU(&hist[d >> BSH], 1u);
    }
    __syncthreads();
    for (int t = threadIdx.x; t < B; t += 1024)
        cntGB[(size_t)blockIdx.x * B + t] = hist[t];
}

// ---------------- pass B1: per-bucket exclusive scan over groups ----------------
__global__ __launch_bounds__(GP) void k_scanG(const u32* __restrict__ cntGB, int B,
                                              u32* __restrict__ gbOff, u32* __restrict__ total) {
    __shared__ u32 s[GP];
    int b = blockIdx.x;
    u32 v = cntGB[(size_t)threadIdx.x * B + b];
    s[threadIdx.x] = v;
    __syncthreads();
    for (int o = 1; o < GP; o <<= 1) {
        u32 t = (threadIdx.x >= (u32)o) ? s[threadIdx.x - o] : 0u;
        __syncthreads();
        s[threadIdx.x] += t;
        __syncthreads();
    }
    gbOff[(size_t)threadIdx.x * B + b] = s[threadIdx.x] - v;
    if (threadIdx.x == GP - 1) total[b] = s[GP - 1];
}

// ---------------- pass B2: bucket starts, padded to 4-entry alignment ----------------
__global__ __launch_bounds__(256) void k_scanB(const u32* __restrict__ total, int B,
                                               u32* __restrict__ bstartP) {
    __shared__ u32 s[256];
    int per = (B + 255) / 256;
    int i0 = threadIdx.x * per;
    int iend = min(B, i0 + per);
    u32 sum = 0u;
    for (int i = i0; i < iend; ++i) sum += (total[i] + 3u) & ~3u;
    s[threadIdx.x] = sum;
    __syncthreads();
    for (int o = 1; o < 256; o <<= 1) {
        u32 t = (threadIdx.x >= (u32)o) ? s[threadIdx.x - o] : 0u;
        __syncthreads();
        s[threadIdx.x] += t;
        __syncthreads();
    }
    u32 run = s[threadIdx.x] - sum;  // exclusive prefix
    for (int i = i0; i < iend; ++i) { bstartP[i] = run; run += (total[i] + 3u) & ~3u; }
}

// ---------------- pass C: partition edges, entry = (src<<8)|dst_local ----------------
__global__ __launch_bounds__(1024) void k_part(const u32* __restrict__ ei, int E, int B,
                                               const u32* __restrict__ flags,
                                               const u32* __restrict__ gbOff,
                                               const u32* __restrict__ bstartP,
                                               u32* __restrict__ bbuf) {
    __shared__ u32 cur[BMAXB];
    for (int t = threadIdx.x; t < B; t += 1024)
        cur[t] = bstartP[t] + gbOff[(size_t)blockIdx.x * B + t];
    __syncthreads();
    u32 strd = flags[0];
    int chunk = (E + GP - 1) / GP;
    int e0 = blockIdx.x * chunk;
    int e1 = min(E, e0 + chunk);
    for (int e = e0 + threadIdx.x; e < e1; e += 1024) {
        u32 sidx = ei[(size_t)e * strd];
        u32 d = ei[((size_t)E + (size_t)e) * strd];
        u32 p = atomicAdd(&cur[d >> BSH], 1u);
        bbuf[p] = (sidx << BSH) | (d & BMASK);
    }
}

// ---------------- pass D: per-bucket CSR finalize (256-node window, 1024 thr) ----------------
__global__ __launch_bounds__(1024) void k_csr(const u32* __restrict__ bbuf,
                                              const u32* __restrict__ bstartP,
                                              const u32* __restrict__ total, int N,
                                              u32* __restrict__ cnt, u32* __restrict__ off,
                                              float* __restrict__ dinv, u32* __restrict__ perm) {
    __shared__ u32 ncnt[BUCKET];
    __shared__ u32 sc[BUCKET];
    __shared__ u32 ncur[BUCKET];
    int b = blockIdx.x;
    u32 base = bstartP[b], tot = total[b];
    if (threadIdx.x < BUCKET) ncnt[threadIdx.x] = 0u;
    __syncthreads();
    u32 nv4 = tot >> 2;
    for (u32 q = threadIdx.x; q < nv4; q += 1024) {
        uint4 e4 = *reinterpret_cast<const uint4*>(bbuf + base + q * 4);
        ldsAddU(&ncnt[e4.x & BMASK], 1u);
        ldsAddU(&ncnt[e4.y & BMASK], 1u);
        ldsAddU(&ncnt[e4.z & BMASK], 1u);
        ldsAddU(&ncnt[e4.w & BMASK], 1u);
    }
    u32 i0 = (nv4 << 2) + threadIdx.x;
    if (i0 < tot) ldsAddU(&ncnt[bbuf[base + i0] & BMASK], 1u);
    __syncthreads();
    u32 v = 0u;
    if (threadIdx.x < BUCKET) { v = ncnt[threadIdx.x]; sc[threadIdx.x] = v; }
    __syncthreads();
    for (int o = 1; o < BUCKET; o <<= 1) {
        u32 t = 0u;
        if (threadIdx.x < BUCKET && threadIdx.x >= (u32)o) t = sc[threadIdx.x - o];
        __syncthreads();
        if (threadIdx.x < BUCKET) sc[threadIdx.x] += t;
        __syncthreads();
    }
    if (threadIdx.x < BUCKET) {
        u32 o = base + (sc[threadIdx.x] - v);    // exclusive
        ncur[threadIdx.x] = o;
        int node = b * BUCKET + (int)threadIdx.x;
        if (node < N) {
            cnt[node] = v;
            off[node] = o;
            dinv[node] = rsqrtf((float)(v + 1u));  // +1 self-loop
        }
    }
    __syncthreads();
    for (u32 q = threadIdx.x; q < nv4; q += 1024) {
        uint4 e4 = *reinterpret_cast<const uint4*>(bbuf + base + q * 4);
        u32 p;
        p = ldsAddURtn(&ncur[e4.x & BMASK], 1u); perm[p] = e4.x >> BSH;
        p = ldsAddURtn(&ncur[e4.y & BMASK], 1u); perm[p] = e4.y >> BSH;
        p = ldsAddURtn(&ncur[e4.z & BMASK], 1u); perm[p] = e4.z >> BSH;
        p = ldsAddURtn(&ncur[e4.w & BMASK], 1u); perm[p] = e4.w >> BSH;
    }
    if (i0 < tot) {
        u32 e = bbuf[base + i0];
        u32 p = ldsAddURtn(&ncur[e & BMASK], 1u);
        perm[p] = e >> BSH;
    }
}

// ---------------- h1s[r,:] = (x[r,:] @ W1) * dinv[r]  (plain [N][16] rows) ----------------
__global__ __launch_bounds__(256) void k_xw1(const float* __restrict__ x, const float* __restrict__ W1,
                                             const float* __restrict__ dinv, float* __restrict__ h1s, int n) {
    __shared__ float Ws[F_IN * H1c];  // 8 KB
    for (int t = threadIdx.x; t < F_IN * H1c; t += 256) Ws[t] = W1[t];
    __syncthreads();
    int r = blockIdx.x * 16 + (threadIdx.x >> 4);
    int c = threadIdx.x & 15;
    if (r >= n) return;
    const float* xr = x + (size_t)r * F_IN;
    float a0 = 0.f, a1 = 0.f;
    #pragma unroll
    for (int k = 0; k < F_IN; k += 4) {
        float4 xv = *reinterpret_cast<const float4*>(xr + k);
        a0 += xv.x * Ws[(k + 0) * H1c + c];
        a1 += xv.y * Ws[(k + 1) * H1c + c];
        a0 += xv.z * Ws[(k + 2) * H1c + c];
        a1 += xv.w * Ws[(k + 3) * H1c + c];
    }
    h1s[(size_t)r * H1c + c] = (a0 + a1) * dinv[r];
}

// ---------------- GCN1 aggregate: 128-thr blocks, 4 lanes/node, unroll 8 ----------------
// p2[node] = relu(dinv*(sum + self) + b1) * dinv
__global__ __launch_bounds__(128) void k_agg1(const float* __restrict__ h1s, const u32* __restrict__ perm,
                                              const u32* __restrict__ off, const u32* __restrict__ cnt,
                                              const float* __restrict__ dinv, const float* __restrict__ b1,
                                              float* __restrict__ p2, int N) {
    int g = threadIdx.x >> 2, l4 = threadIdx.x & 3;
    int node = blockIdx.x * 32 + g;
    if (node >= N) return;
    u32 s0 = off[node], len = cnt[node];
    int fo = l4 * 4;
    float x0 = 0.f, y0 = 0.f, z0 = 0.f, w0 = 0.f;
    float x1 = 0.f, y1 = 0.f, z1 = 0.f, w1 = 0.f;
    float x2 = 0.f, y2 = 0.f, z2 = 0.f, w2 = 0.f;
    float x3 = 0.f, y3 = 0.f, z3 = 0.f, w3 = 0.f;
    u32 it = 0;
    for (; it + 8 <= len; it += 8) {
        u32 e0 = perm[s0 + it],     e1 = perm[s0 + it + 1];
        u32 e2 = perm[s0 + it + 2], e3 = perm[s0 + it + 3];
        u32 e4 = perm[s0 + it + 4], e5 = perm[s0 + it + 5];
        u32 e6 = perm[s0 + it + 6], e7 = perm[s0 + it + 7];
        float4 v0 = *reinterpret_cast<const float4*>(h1s + (size_t)e0 * H1c + fo);
        float4 v1 = *reinterpret_cast<const float4*>(h1s + (size_t)e1 * H1c + fo);
        float4 v2 = *reinterpret_cast<const float4*>(h1s + (size_t)e2 * H1c + fo);
        float4 v3 = *reinterpret_cast<const float4*>(h1s + (size_t)e3 * H1c + fo);
        float4 v4 = *reinterpret_cast<const float4*>(h1s + (size_t)e4 * H1c + fo);
        float4 v5 = *reinterpret_cast<const float4*>(h1s + (size_t)e5 * H1c + fo);
        float4 v6 = *reinterpret_cast<const float4*>(h1s + (size_t)e6 * H1c + fo);
        float4 v7 = *reinterpret_cast<const float4*>(h1s + (size_t)e7 * H1c + fo);
        x0 += v0.x; y0 += v0.y; z0 += v0.z; w0 += v0.w;
        x1 += v1.x; y1 += v1.y; z1 += v1.z; w1 += v1.w;
        x2 += v2.x; y2 += v2.y; z2 += v2.z; w2 += v2.w;
        x3 += v3.x; y3 += v3.y; z3 += v3.z; w3 += v3.w;
        x0 += v4.x; y0 += v4.y; z0 += v4.z; w0 += v4.w;
        x1 += v5.x; y1 += v5.y; z1 += v5.z; w1 += v5.w;
        x2 += v6.x; y2 += v6.y; z2 += v6.z; w2 += v6.w;
        x3 += v7.x; y3 += v7.y; z3 += v7.z; w3 += v7.w;
    }
    for (; it < len; ++it) {
        u32 e = perm[s0 + it];
        float4 v = *reinterpret_cast<const float4*>(h1s + (size_t)e * H1c + fo);
        x0 += v.x; y0 += v.y; z0 += v.z; w0 += v.w;
    }
    float4 self = *reinterpret_cast<const float4*>(h1s + (size_t)node * H1c + fo);
    float dv = dinv[node];
    float4 bv = *reinterpret_cast<const float4*>(b1 + fo);
    float4 r;
    r.x = fmaxf(dv * ((x0 + x1) + (x2 + x3) + self.x) + bv.x, 0.f) * dv;
    r.y = fmaxf(dv * ((y0 + y1) + (y2 + y3) + self.y) + bv.y, 0.f) * dv;
    r.z = fmaxf(dv * ((z0 + z1) + (z2 + z3) + self.z) + bv.z, 0.f) * dv;
    r.w = fmaxf(dv * ((w0 + w1) + (w2 + w3) + self.w) + bv.w, 0.f) * dv;
    *reinterpret_cast<float4*>(p2 + (size_t)node * H1c + fo) = r;
}

// ---------------- GCN2 aggregate (128-thr, unroll 8) + @W2 + bias + ReLU ----------------
__global__ __launch_bounds__(128) void k_agg2w2(const float* __restrict__ p2, const u32* __restrict__ perm,
                                                const u32* __restrict__ off, const u32* __restrict__ cnt,
                                                const float* __restrict__ dinv, const float* __restrict__ W2,
                                                const float* __restrict__ b2, float* __restrict__ h2post,
                                                int N) {
    __shared__ float hL[32][H1c + 1];
    __shared__ float W2s[H1c * H2c];
    __shared__ float b2s[H2c];
    for (int t = threadIdx.x; t < H1c * H2c; t += 128) W2s[t] = W2[t];
    if (threadIdx.x < H2c) b2s[threadIdx.x] = b2[threadIdx.x];

    int g = threadIdx.x >> 2, l4 = threadIdx.x & 3;
    int node = blockIdx.x * 32 + g;
    int fo = l4 * 4;
    float rx = 0.f, ry = 0.f, rz = 0.f, rw = 0.f;
    if (node < N) {
        u32 s0 = off[node], len = cnt[node];
        float x0 = 0.f, y0 = 0.f, z0 = 0.f, w0 = 0.f;
        float x1 = 0.f, y1 = 0.f, z1 = 0.f, w1 = 0.f;
        float x2 = 0.f, y2 = 0.f, z2 = 0.f, w2 = 0.f;
        float x3 = 0.f, y3 = 0.f, z3 = 0.f, w3 = 0.f;
        u32 it = 0;
        for (; it + 8 <= len; it += 8) {
            u32 e0 = perm[s0 + it],     e1 = perm[s0 + it + 1];
            u32 e2 = perm[s0 + it + 2], e3 = perm[s0 + it + 3];
            u32 e4 = perm[s0 + it + 4], e5 = perm[s0 + it + 5];
            u32 e6 = perm[s0 + it + 6], e7 = perm[s0 + it + 7];
            float4 v0 = *reinterpret_cast<const float4*>(p2 + (size_t)e0 * H1c + fo);
            float4 v1 = *reinterpret_cast<const float4*>(p2 + (size_t)e1 * H1c + fo);
            float4 v2 = *reinterpret_cast<const float4*>(p2 + (size_t)e2 * H1c + fo);
            float4 v3 = *reinterpret_cast<const float4*>(p2 + (size_t)e3 * H1c + fo);
            float4 v4 = *reinterpret_cast<const float4*>(p2 + (size_t)e4 * H1c + fo);
            float4 v5 = *reinterpret_cast<const float4*>(p2 + (size_t)e5 * H1c + fo);
            float4 v6 = *reinterpret_cast<const float4*>(p2 + (size_t)e6 * H1c + fo);
            float4 v7 = *reinterpret_cast<const float4*>(p2 + (size_t)e7 * H1c + fo);
            x0 += v0.x; y0 += v0.y; z0 += v0.z; w0 += v0.w;
            x1 += v1.x; y1 += v1.y; z1 += v1.z; w1 += v1.w;
            x2 += v2.x; y2 += v2.y; z2 += v2.z; w2 += v2.w;
            x3 += v3.x; y3 += v3.y; z3 += v3.z; w3 += v3.w;
            x0 += v4.x; y0 += v4.y; z0 += v4.z; w0 += v4.w;
            x1 += v5.x; y1 += v5.y; z1 += v5.z; w1 += v5.w;
            x2 += v6.x; y2 += v6.y; z2 += v6.z; w2 += v6.w;
            x3 += v7.x; y3 += v7.y; z3 += v7.z; w3 += v7.w;
        }
        for (; it < len; ++it) {
            u32 e = perm[s0 + it];
            float4 v = *reinterpret_cast<const float4*>(p2 + (size_t)e * H1c + fo);
            x0 += v.x; y0 += v.y; z0 += v.z; w0 += v.w;
        }
        float4 self = *reinterpret_cast<const float4*>(p2 + (size_t)node * H1c + fo);
        float dv = dinv[node];
        rx = dv * ((x0 + x1) + (x2 + x3) + self.x);
        ry = dv * ((y0 + y1) + (y2 + y3) + self.y);
        rz = dv * ((z0 + z1) + (z2 + z3) + self.z);
        rw = dv * ((w0 + w1) + (w2 + w3) + self.w);
    }
    hL[g][fo + 0] = rx;
    hL[g][fo + 1] = ry;
    hL[g][fo + 2] = rz;
    hL[g][fo + 3] = rw;
    __syncthreads();

    int nbase = blockIdx.x * 32;
    #pragma unroll
    for (int rep = 0; rep < 8; ++rep) {
        int o = threadIdx.x + rep * 128;
        int nl = o >> 5, c = o & 31;
        int n2 = nbase + nl;
        if (n2 < N) {
            float s = b2s[c];
            #pragma unroll
            for (int k = 0; k < H1c; ++k) s += hL[nl][k] * W2s[k * H2c + c];
            h2post[(size_t)n2 * H2c + c] = fmaxf(s, 0.f);
        }
    }
}

// ---------------- fused MLP (plain [N][32] h2post) ----------------
__global__ __launch_bounds__(256) void k_mlp(const float* __restrict__ h2post,
                                             const float* __restrict__ Wf1, const float* __restrict__ bf1,
                                             const float* __restrict__ Wf2, const float* __restrict__ bf2,
                                             const float* __restrict__ Wf3, const float* __restrict__ bf3,
                                             float* __restrict__ out, int n) {
    __shared__ float W1s[H2c * H3c];
    __shared__ float W2s[H3c * H4c];
    __shared__ float W3s[H4c * NCc];
    __shared__ float b1s[H3c], b2s[H4c], b3s[NCc];
    for (int t = threadIdx.x; t < H2c * H3c; t += 256) W1s[t] = Wf1[t];
    for (int t = threadIdx.x; t < H3c * H4c; t += 256) W2s[t] = Wf2[t];
    for (int t = threadIdx.x; t < H4c * NCc; t += 256) W3s[t] = Wf3[t];
    if (threadIdx.x < H3c) b1s[threadIdx.x] = bf1[threadIdx.x];
    if (threadIdx.x < H4c) b2s[threadIdx.x] = bf2[threadIdx.x];
    if (threadIdx.x < NCc) b3s[threadIdx.x] = bf3[threadIdx.x];
    __syncthreads();

    int r = blockIdx.x * 256 + threadIdx.x;
    if (r >= n) return;

    float h2v[H2c];
    #pragma unroll
    for (int k = 0; k < H2c; k += 4) {
        float4 v = *reinterpret_cast<const float4*>(h2post + (size_t)r * H2c + k);
        h2v[k] = v.x; h2v[k + 1] = v.y; h2v[k + 2] = v.z; h2v[k + 3] = v.w;
    }
    float a4[H4c];
    #pragma unroll
    for (int k2 = 0; k2 < H4c; ++k2) a4[k2] = b2s[k2];
    #pragma unroll 4
    for (int j = 0; j < H3c; ++j) {
        float t = b1s[j];
        #pragma unroll
        for (int k = 0; k < H2c; ++k) t += h2v[k] * W1s[k * H3c + j];
        t = fmaxf(t, 0.f);
        #pragma unroll
        for (int k2 = 0; k2 < H4c; ++k2) a4[k2] += t * W2s[j * H4c + k2];
    }
    #pragma unroll
    for (int k2 = 0; k2 < H4c; ++k2) a4[k2] = fmaxf(a4[k2], 0.f);

    #pragma unroll
    for (int c0 = 0; c0 < NCc; c0 += 4) {
        float o0 = b3s[c0], o1 = b3s[c0 + 1], o2 = b3s[c0 + 2], o3 = b3s[c0 + 3];
        #pragma unroll
        for (int k2 = 0; k2 < H4c; ++k2) {
            float a = a4[k2];
            o0 += a * W3s[k2 * NCc + c0];
            o1 += a * W3s[k2 * NCc + c0 + 1];
            o2 += a * W3s[k2 * NCc + c0 + 2];
            o3 += a * W3s[k2 * NCc + c0 + 3];
        }
        *reinterpret_cast<float4*>(out + (size_t)r * NCc + c0) = make_float4(o0, o1, o2, o3);
    }
}

extern "C" void kernel_launch(void* const* d_in, const int* in_sizes, int n_in,
                              void* d_out, int out_size, void* d_ws, size_t ws_size,
                              hipStream_t stream) {
    const float* x   = (const float*)d_in[0];
    const float* W1  = (const float*)d_in[1];
    const float* b1  = (const float*)d_in[2];
    const float* W2  = (const float*)d_in[3];
    const float* b2  = (const float*)d_in[4];
    const float* Wf1 = (const float*)d_in[5];
    const float* bf1 = (const float*)d_in[6];
    const float* Wf2 = (const float*)d_in[7];
    const float* bf2 = (const float*)d_in[8];
    const float* Wf3 = (const float*)d_in[9];
    const float* bf3 = (const float*)d_in[10];
    const u32*   ei  = (const u32*)d_in[11];

    int N = in_sizes[0] / F_IN;
    int E = in_sizes[11] / 2;
    int B = (N + BUCKET - 1) >> BSH;
    if (B > BMAXB) return;           // fixed-size problem guard

    // workspace layout (16B-aligned segments)
    char* w = (char*)d_ws;
    u32* flags  = (u32*)w;   w += 64;
    float* dinv = (float*)w; w += (size_t)((N + 3) & ~3) * 4;
    u32* cnt    = (u32*)w;   w += (size_t)((N + 3) & ~3) * 4;
    u32* off    = (u32*)w;   w += (size_t)((N + 3) & ~3) * 4;
    float* h2p  = (float*)w; w += (size_t)N * H2c * 4;      // h2post [N][32]
    u32* perm   = (u32*)w;   w += ((size_t)E + 4096) * 4;
    u32* bbuf   = (u32*)w;   w += ((size_t)E + 4096) * 4;   // dead after k_csr
    u32* cntGB  = (u32*)w;   w += (size_t)GP * BMAXB * 4;
    u32* gbOff  = (u32*)w;   w += (size_t)GP * BMAXB * 4;
    u32* total  = (u32*)w;   w += (size_t)(BMAXB + 8) * 4;
    u32* bstartP= (u32*)w;   w += (size_t)(BMAXB + 8) * 4;
    // alias bbuf (dead after k_csr): h1s [N][16] + p2 [N][16]  (N*32 u32 <= E)
    float* h1s = (float*)bbuf;
    float* p2  = h1s + (size_t)N * H1c;

    k_detect<<<1, 256, 0, stream>>>(ei, flags);
    k_hist  <<<GP, 1024, 0, stream>>>(ei, E, B, flags, cntGB);
    k_scanG <<<B, GP, 0, stream>>>(cntGB, B, gbOff, total);
    k_scanB <<<1, 256, 0, stream>>>(total, B, bstartP);
    k_part  <<<GP, 1024, 0, stream>>>(ei, E, B, flags, gbOff, bstartP, bbuf);
    k_csr   <<<B, 1024, 0, stream>>>(bbuf, bstartP, total, N, cnt, off, dinv, perm);

    int nb16 = (N + 15) / 16;
    k_xw1<<<nb16, 256, 0, stream>>>(x, W1, dinv, h1s, N);
    int nb32 = (N + 31) / 32;
    k_agg1<<<nb32, 128, 0, stream>>>(h1s, perm, off, cnt, dinv, b1, p2, N);
    k_agg2w2<<<nb32, 128, 0, stream>>>(p2, perm, off, cnt, dinv, W2, b2, h2p, N);
    int nbN = (N + 255) / 256;
    k_mlp<<<nbN, 256, 0, stream>>>(h2p, Wf1, bf1, Wf2, bf2, Wf3, bf3, (float*)d_out, N);
}

// Round 12
// 440.460 us; speedup vs baseline: 1.4667x; 1.1184x over previous
//
#include <hip/hip_runtime.h>
#include <hip/hip_bf16.h>
#include <hip/hip_fp16.h>
#include <math.h>

#define F_IN 128
#define H1c 16
#define H2c 32
#define H3c 64
#define H4c 32
#define NCc 16

#define BUCKET 256
#define BSH 8
#define BMASK 255u
#define BMAXB 512        // max buckets (N <= 131072)
#define GP 512           // partition groups (grid of hist/part kernels)

typedef unsigned int u32;

static __device__ __forceinline__ void ldsAddU(u32* p, u32 v) {
    __hip_atomic_fetch_add(p, v, __ATOMIC_RELAXED, __HIP_MEMORY_SCOPE_WORKGROUP);
}
static __device__ __forceinline__ u32 ldsAddURtn(u32* p, u32 v) {
    return __hip_atomic_fetch_add(p, v, __ATOMIC_RELAXED, __HIP_MEMORY_SCOPE_WORKGROUP);
}
// load 4 halves (8B) -> float4
static __device__ __forceinline__ float4 ldh4(const __half* p) {
    uint2 u = *reinterpret_cast<const uint2*>(p);
    __half2 h0 = *reinterpret_cast<__half2*>(&u.x);
    __half2 h1 = *reinterpret_cast<__half2*>(&u.y);
    float2 f0 = __half22float2(h0);
    float2 f1 = __half22float2(h1);
    return make_float4(f0.x, f0.y, f1.x, f1.y);
}
// store float4 -> 4 halves (8B)
static __device__ __forceinline__ void sth4(__half* p, float4 v) {
    __half2 h0 = __floats2half2_rn(v.x, v.y);
    __half2 h1 = __floats2half2_rn(v.z, v.w);
    uint2 u;
    u.x = *reinterpret_cast<unsigned*>(&h0);
    u.y = *reinterpret_cast<unsigned*>(&h1);
    *reinterpret_cast<uint2*>(p) = u;
}

// ---------------- edge dtype detect ----------------
__global__ __launch_bounds__(256) void k_detect(const u32* __restrict__ ei, u32* __restrict__ flags) {
    __shared__ int nz;
    if (threadIdx.x == 0) nz = 0;
    __syncthreads();
    for (int i = threadIdx.x; 2 * i + 1 < 8192; i += blockDim.x) {
        if (ei[2 * i + 1] != 0u) atomicAdd(&nz, 1);
    }
    __syncthreads();
    if (threadIdx.x == 0) flags[0] = (nz == 0) ? 2u : 1u;
}

// ---------------- pass A: per-group bucket histogram ----------------
__global__ __launch_bounds__(1024) void k_hist(const u32* __restrict__ ei, int E, int B,
                                               const u32* __restrict__ flags,
                                               u32* __restrict__ cntGB) {
    __shared__ u32 hist[BMAXB];
    for (int t = threadIdx.x; t < B; t += 1024) hist[t] = 0u;
    __syncthreads();
    u32 strd = flags[0];
    int chunk = (E + GP - 1) / GP;
    int e0 = blockIdx.x * chunk;
    int e1 = min(E, e0 + chunk);
    for (int e = e0 + threadIdx.x; e < e1; e += 1024) {
        u32 d = ei[((size_t)E + (size_t)e) * strd];
        ldsAddU(&hist[d >> BSH], 1u);
    }
    __syncthreads();
    for (int t = threadIdx.x; t < B; t += 1024)
        cntGB[(size_t)blockIdx.x * B + t] = hist[t];
}

// ---------------- pass B1: per-bucket exclusive scan over groups ----------------
__global__ __launch_bounds__(GP) void k_scanG(const u32* __restrict__ cntGB, int B,
                                              u32* __restrict__ gbOff, u32* __restrict__ total) {
    __shared__ u32 s[GP];
    int b = blockIdx.x;
    u32 v = cntGB[(size_t)threadIdx.x * B + b];
    s[threadIdx.x] = v;
    __syncthreads();
    for (int o = 1; o < GP; o <<= 1) {
        u32 t = (threadIdx.x >= (u32)o) ? s[threadIdx.x - o] : 0u;
        __syncthreads();
        s[threadIdx.x] += t;
        __syncthreads();
    }
    gbOff[(size_t)threadIdx.x * B + b] = s[threadIdx.x] - v;
    if (threadIdx.x == GP - 1) total[b] = s[GP - 1];
}

// ---------------- pass B2: bucket starts, padded to 4-entry alignment ----------------
__global__ __launch_bounds__(256) void k_scanB(const u32* __restrict__ total, int B,
                                               u32* __restrict__ bstartP) {
    __shared__ u32 s[256];
    int per = (B + 255) / 256;
    int i0 = threadIdx.x * per;
    int iend = min(B, i0 + per);
    u32 sum = 0u;
    for (int i = i0; i < iend; ++i) sum += (total[i] + 3u) & ~3u;
    s[threadIdx.x] = sum;
    __syncthreads();
    for (int o = 1; o < 256; o <<= 1) {
        u32 t = (threadIdx.x >= (u32)o) ? s[threadIdx.x - o] : 0u;
        __syncthreads();
        s[threadIdx.x] += t;
        __syncthreads();
    }
    u32 run = s[threadIdx.x] - sum;  // exclusive prefix
    for (int i = i0; i < iend; ++i) { bstartP[i] = run; run += (total[i] + 3u) & ~3u; }
}

// ---------------- pass C: partition edges, entry = (src<<8)|dst_local ----------------
__global__ __launch_bounds__(1024) void k_part(const u32* __restrict__ ei, int E, int B,
                                               const u32* __restrict__ flags,
                                               const u32* __restrict__ gbOff,
                                               const u32* __restrict__ bstartP,
                                               u32* __restrict__ bbuf) {
    __shared__ u32 cur[BMAXB];
    for (int t = threadIdx.x; t < B; t += 1024)
        cur[t] = bstartP[t] + gbOff[(size_t)blockIdx.x * B + t];
    __syncthreads();
    u32 strd = flags[0];
    int chunk = (E + GP - 1) / GP;
    int e0 = blockIdx.x * chunk;
    int e1 = min(E, e0 + chunk);
    for (int e = e0 + threadIdx.x; e < e1; e += 1024) {
        u32 sidx = ei[(size_t)e * strd];
        u32 d = ei[((size_t)E + (size_t)e) * strd];
        u32 p = atomicAdd(&cur[d >> BSH], 1u);
        bbuf[p] = (sidx << BSH) | (d & BMASK);
    }
}

// ---------------- pass D: per-bucket CSR finalize (256-node window, 1024 thr) ----------------
__global__ __launch_bounds__(1024) void k_csr(const u32* __restrict__ bbuf,
                                              const u32* __restrict__ bstartP,
                                              const u32* __restrict__ total, int N,
                                              u32* __restrict__ cnt, u32* __restrict__ off,
                                              float* __restrict__ dinv, u32* __restrict__ perm) {
    __shared__ u32 ncnt[BUCKET];
    __shared__ u32 sc[BUCKET];
    __shared__ u32 ncur[BUCKET];
    int b = blockIdx.x;
    u32 base = bstartP[b], tot = total[b];
    if (threadIdx.x < BUCKET) ncnt[threadIdx.x] = 0u;
    __syncthreads();
    u32 nv4 = tot >> 2;
    for (u32 q = threadIdx.x; q < nv4; q += 1024) {
        uint4 e4 = *reinterpret_cast<const uint4*>(bbuf + base + q * 4);
        ldsAddU(&ncnt[e4.x & BMASK], 1u);
        ldsAddU(&ncnt[e4.y & BMASK], 1u);
        ldsAddU(&ncnt[e4.z & BMASK], 1u);
        ldsAddU(&ncnt[e4.w & BMASK], 1u);
    }
    u32 i0 = (nv4 << 2) + threadIdx.x;
    if (i0 < tot) ldsAddU(&ncnt[bbuf[base + i0] & BMASK], 1u);
    __syncthreads();
    u32 v = 0u;
    if (threadIdx.x < BUCKET) { v = ncnt[threadIdx.x]; sc[threadIdx.x] = v; }
    __syncthreads();
    for (int o = 1; o < BUCKET; o <<= 1) {
        u32 t = 0u;
        if (threadIdx.x < BUCKET && threadIdx.x >= (u32)o) t = sc[threadIdx.x - o];
        __syncthreads();
        if (threadIdx.x < BUCKET) sc[threadIdx.x] += t;
        __syncthreads();
    }
    if (threadIdx.x < BUCKET) {
        u32 o = base + (sc[threadIdx.x] - v);    // exclusive
        ncur[threadIdx.x] = o;
        int node = b * BUCKET + (int)threadIdx.x;
        if (node < N) {
            cnt[node] = v;
            off[node] = o;
            dinv[node] = rsqrtf((float)(v + 1u));  // +1 self-loop
        }
    }
    __syncthreads();
    for (u32 q = threadIdx.x; q < nv4; q += 1024) {
        uint4 e4 = *reinterpret_cast<const uint4*>(bbuf + base + q * 4);
        u32 p;
        p = ldsAddURtn(&ncur[e4.x & BMASK], 1u); perm[p] = e4.x >> BSH;
        p = ldsAddURtn(&ncur[e4.y & BMASK], 1u); perm[p] = e4.y >> BSH;
        p = ldsAddURtn(&ncur[e4.z & BMASK], 1u); perm[p] = e4.z >> BSH;
        p = ldsAddURtn(&ncur[e4.w & BMASK], 1u); perm[p] = e4.w >> BSH;
    }
    if (i0 < tot) {
        u32 e = bbuf[base + i0];
        u32 p = ldsAddURtn(&ncur[e & BMASK], 1u);
        perm[p] = e >> BSH;
    }
}

// ---------------- h1h[r,:] = fp16((x[r,:] @ W1) * dinv[r])  ([N][16] half rows) ----------------
__global__ __launch_bounds__(256) void k_xw1(const float* __restrict__ x, const float* __restrict__ W1,
                                             const float* __restrict__ dinv, __half* __restrict__ h1h, int n) {
    __shared__ float Ws[F_IN * H1c];  // 8 KB
    __shared__ float sx[16][17];
    for (int t = threadIdx.x; t < F_IN * H1c; t += 256) Ws[t] = W1[t];
    __syncthreads();
    int row = threadIdx.x >> 4;
    int c = threadIdx.x & 15;
    int r = blockIdx.x * 16 + row;
    float val = 0.f;
    if (r < n) {
        const float* xr = x + (size_t)r * F_IN;
        float a0 = 0.f, a1 = 0.f;
        #pragma unroll
        for (int k = 0; k < F_IN; k += 4) {
            float4 xv = *reinterpret_cast<const float4*>(xr + k);
            a0 += xv.x * Ws[(k + 0) * H1c + c];
            a1 += xv.y * Ws[(k + 1) * H1c + c];
            a0 += xv.z * Ws[(k + 2) * H1c + c];
            a1 += xv.w * Ws[(k + 3) * H1c + c];
        }
        val = (a0 + a1) * dinv[r];
    }
    sx[row][c] = val;
    __syncthreads();
    if (threadIdx.x < 64) {
        int rw = threadIdx.x >> 2, grp = threadIdx.x & 3;
        int rg = blockIdx.x * 16 + rw;
        if (rg < n) {
            float4 v = make_float4(sx[rw][grp * 4], sx[rw][grp * 4 + 1],
                                   sx[rw][grp * 4 + 2], sx[rw][grp * 4 + 3]);
            sth4(h1h + (size_t)rg * H1c + grp * 4, v);
        }
    }
}

// ---------------- GCN1 aggregate: fp16 rows, 4 lanes/node x 8B, unroll 8 ----------------
// p2[node] = fp16(relu(dinv*(sum + self) + b1) * dinv)
__global__ __launch_bounds__(128) void k_agg1(const __half* __restrict__ h1h, const u32* __restrict__ perm,
                                              const u32* __restrict__ off, const u32* __restrict__ cnt,
                                              const float* __restrict__ dinv, const float* __restrict__ b1,
                                              __half* __restrict__ p2, int N) {
    int g = threadIdx.x >> 2, l4 = threadIdx.x & 3;
    int node = blockIdx.x * 32 + g;
    if (node >= N) return;
    u32 s0 = off[node], len = cnt[node];
    int fo = l4 * 4;
    float x0 = 0.f, y0 = 0.f, z0 = 0.f, w0 = 0.f;
    float x1 = 0.f, y1 = 0.f, z1 = 0.f, w1 = 0.f;
    float x2 = 0.f, y2 = 0.f, z2 = 0.f, w2 = 0.f;
    float x3 = 0.f, y3 = 0.f, z3 = 0.f, w3 = 0.f;
    u32 it = 0;
    for (; it + 8 <= len; it += 8) {
        u32 e0 = perm[s0 + it],     e1 = perm[s0 + it + 1];
        u32 e2 = perm[s0 + it + 2], e3 = perm[s0 + it + 3];
        u32 e4 = perm[s0 + it + 4], e5 = perm[s0 + it + 5];
        u32 e6 = perm[s0 + it + 6], e7 = perm[s0 + it + 7];
        float4 v0 = ldh4(h1h + (size_t)e0 * H1c + fo);
        float4 v1 = ldh4(h1h + (size_t)e1 * H1c + fo);
        float4 v2 = ldh4(h1h + (size_t)e2 * H1c + fo);
        float4 v3 = ldh4(h1h + (size_t)e3 * H1c + fo);
        float4 v4 = ldh4(h1h + (size_t)e4 * H1c + fo);
        float4 v5 = ldh4(h1h + (size_t)e5 * H1c + fo);
        float4 v6 = ldh4(h1h + (size_t)e6 * H1c + fo);
        float4 v7 = ldh4(h1h + (size_t)e7 * H1c + fo);
        x0 += v0.x; y0 += v0.y; z0 += v0.z; w0 += v0.w;
        x1 += v1.x; y1 += v1.y; z1 += v1.z; w1 += v1.w;
        x2 += v2.x; y2 += v2.y; z2 += v2.z; w2 += v2.w;
        x3 += v3.x; y3 += v3.y; z3 += v3.z; w3 += v3.w;
        x0 += v4.x; y0 += v4.y; z0 += v4.z; w0 += v4.w;
        x1 += v5.x; y1 += v5.y; z1 += v5.z; w1 += v5.w;
        x2 += v6.x; y2 += v6.y; z2 += v6.z; w2 += v6.w;
        x3 += v7.x; y3 += v7.y; z3 += v7.z; w3 += v7.w;
    }
    for (; it < len; ++it) {
        u32 e = perm[s0 + it];
        float4 v = ldh4(h1h + (size_t)e * H1c + fo);
        x0 += v.x; y0 += v.y; z0 += v.z; w0 += v.w;
    }
    float4 self = ldh4(h1h + (size_t)node * H1c + fo);
    float dv = dinv[node];
    float4 bv = *reinterpret_cast<const float4*>(b1 + fo);
    float4 r;
    r.x = fmaxf(dv * ((x0 + x1) + (x2 + x3) + self.x) + bv.x, 0.f) * dv;
    r.y = fmaxf(dv * ((y0 + y1) + (y2 + y3) + self.y) + bv.y, 0.f) * dv;
    r.z = fmaxf(dv * ((z0 + z1) + (z2 + z3) + self.z) + bv.z, 0.f) * dv;
    r.w = fmaxf(dv * ((w0 + w1) + (w2 + w3) + self.w) + bv.w, 0.f) * dv;
    sth4(p2 + (size_t)node * H1c + fo, r);
}

// ---------------- GCN2 aggregate (fp16 rows, unroll 8) + @W2 + bias + ReLU ----------------
__global__ __launch_bounds__(128) void k_agg2w2(const __half* __restrict__ p2, const u32* __restrict__ perm,
                                                const u32* __restrict__ off, const u32* __restrict__ cnt,
                                                const float* __restrict__ dinv, const float* __restrict__ W2,
                                                const float* __restrict__ b2, float* __restrict__ h2post,
                                                int N) {
    __shared__ float hL[32][H1c + 1];
    __shared__ float W2s[H1c * H2c];
    __shared__ float b2s[H2c];
    for (int t = threadIdx.x; t < H1c * H2c; t += 128) W2s[t] = W2[t];
    if (threadIdx.x < H2c) b2s[threadIdx.x] = b2[threadIdx.x];

    int g = threadIdx.x >> 2, l4 = threadIdx.x & 3;
    int node = blockIdx.x * 32 + g;
    int fo = l4 * 4;
    float rx = 0.f, ry = 0.f, rz = 0.f, rw = 0.f;
    if (node < N) {
        u32 s0 = off[node], len = cnt[node];
        float x0 = 0.f, y0 = 0.f, z0 = 0.f, w0 = 0.f;
        float x1 = 0.f, y1 = 0.f, z1 = 0.f, w1 = 0.f;
        float x2 = 0.f, y2 = 0.f, z2 = 0.f, w2 = 0.f;
        float x3 = 0.f, y3 = 0.f, z3 = 0.f, w3 = 0.f;
        u32 it = 0;
        for (; it + 8 <= len; it += 8) {
            u32 e0 = perm[s0 + it],     e1 = perm[s0 + it + 1];
            u32 e2 = perm[s0 + it + 2], e3 = perm[s0 + it + 3];
            u32 e4 = perm[s0 + it + 4], e5 = perm[s0 + it + 5];
            u32 e6 = perm[s0 + it + 6], e7 = perm[s0 + it + 7];
            float4 v0 = ldh4(p2 + (size_t)e0 * H1c + fo);
            float4 v1 = ldh4(p2 + (size_t)e1 * H1c + fo);
            float4 v2 = ldh4(p2 + (size_t)e2 * H1c + fo);
            float4 v3 = ldh4(p2 + (size_t)e3 * H1c + fo);
            float4 v4 = ldh4(p2 + (size_t)e4 * H1c + fo);
            float4 v5 = ldh4(p2 + (size_t)e5 * H1c + fo);
            float4 v6 = ldh4(p2 + (size_t)e6 * H1c + fo);
            float4 v7 = ldh4(p2 + (size_t)e7 * H1c + fo);
            x0 += v0.x; y0 += v0.y; z0 += v0.z; w0 += v0.w;
            x1 += v1.x; y1 += v1.y; z1 += v1.z; w1 += v1.w;
            x2 += v2.x; y2 += v2.y; z2 += v2.z; w2 += v2.w;
            x3 += v3.x; y3 += v3.y; z3 += v3.z; w3 += v3.w;
            x0 += v4.x; y0 += v4.y; z0 += v4.z; w0 += v4.w;
            x1 += v5.x; y1 += v5.y; z1 += v5.z; w1 += v5.w;
            x2 += v6.x; y2 += v6.y; z2 += v6.z; w2 += v6.w;
            x3 += v7.x; y3 += v7.y; z3 += v7.z; w3 += v7.w;
        }
        for (; it < len; ++it) {
            u32 e = perm[s0 + it];
            float4 v = ldh4(p2 + (size_t)e * H1c + fo);
            x0 += v.x; y0 += v.y; z0 += v.z; w0 += v.w;
        }
        float4 self = ldh4(p2 + (size_t)node * H1c + fo);
        float dv = dinv[node];
        rx = dv * ((x0 + x1) + (x2 + x3) + self.x);
        ry = dv * ((y0 + y1) + (y2 + y3) + self.y);
        rz = dv * ((z0 + z1) + (z2 + z3) + self.z);
        rw = dv * ((w0 + w1) + (w2 + w3) + self.w);
    }
    hL[g][fo + 0] = rx;
    hL[g][fo + 1] = ry;
    hL[g][fo + 2] = rz;
    hL[g][fo + 3] = rw;
    __syncthreads();

    int nbase = blockIdx.x * 32;
    #pragma unroll
    for (int rep = 0; rep < 8; ++rep) {
        int o = threadIdx.x + rep * 128;
        int nl = o >> 5, c = o & 31;
        int n2 = nbase + nl;
        if (n2 < N) {
            float s = b2s[c];
            #pragma unroll
            for (int k = 0; k < H1c; ++k) s += hL[nl][k] * W2s[k * H2c + c];
            h2post[(size_t)n2 * H2c + c] = fmaxf(s, 0.f);
        }
    }
}

// ---------------- fused MLP (plain [N][32] h2post) ----------------
__global__ __launch_bounds__(256) void k_mlp(const float* __restrict__ h2post,
                                             const float* __restrict__ Wf1, const float* __restrict__ bf1,
                                             const float* __restrict__ Wf2, const float* __restrict__ bf2,
                                             const float* __restrict__ Wf3, const float* __restrict__ bf3,
                                             float* __restrict__ out, int n) {
    __shared__ float W1s[H2c * H3c];
    __shared__ float W2s[H3c * H4c];
    __shared__ float W3s[H4c * NCc];
    __shared__ float b1s[H3c], b2s[H4c], b3s[NCc];
    for (int t = threadIdx.x; t < H2c * H3c; t += 256) W1s[t] = Wf1[t];
    for (int t = threadIdx.x; t < H3c * H4c; t += 256) W2s[t] = Wf2[t];
    for (int t = threadIdx.x; t < H4c * NCc; t += 256) W3s[t] = Wf3[t];
    if (threadIdx.x < H3c) b1s[threadIdx.x] = bf1[threadIdx.x];
    if (threadIdx.x < H4c) b2s[threadIdx.x] = bf2[threadIdx.x];
    if (threadIdx.x < NCc) b3s[threadIdx.x] = bf3[threadIdx.x];
    __syncthreads();

    int r = blockIdx.x * 256 + threadIdx.x;
    if (r >= n) return;

    float h2v[H2c];
    #pragma unroll
    for (int k = 0; k < H2c; k += 4) {
        float4 v = *reinterpret_cast<const float4*>(h2post + (size_t)r * H2c + k);
        h2v[k] = v.x; h2v[k + 1] = v.y; h2v[k + 2] = v.z; h2v[k + 3] = v.w;
    }
    float a4[H4c];
    #pragma unroll
    for (int k2 = 0; k2 < H4c; ++k2) a4[k2] = b2s[k2];
    #pragma unroll 4
    for (int j = 0; j < H3c; ++j) {
        float t = b1s[j];
        #pragma unroll
        for (int k = 0; k < H2c; ++k) t += h2v[k] * W1s[k * H3c + j];
        t = fmaxf(t, 0.f);
        #pragma unroll
        for (int k2 = 0; k2 < H4c; ++k2) a4[k2] += t * W2s[j * H4c + k2];
    }
    #pragma unroll
    for (int k2 = 0; k2 < H4c; ++k2) a4[k2] = fmaxf(a4[k2], 0.f);

    #pragma unroll
    for (int c0 = 0; c0 < NCc; c0 += 4) {
        float o0 = b3s[c0], o1 = b3s[c0 + 1], o2 = b3s[c0 + 2], o3 = b3s[c0 + 3];
        #pragma unroll
        for (int k2 = 0; k2 < H4c; ++k2) {
            float a = a4[k2];
            o0 += a * W3s[k2 * NCc + c0];
            o1 += a * W3s[k2 * NCc + c0 + 1];
            o2 += a * W3s[k2 * NCc + c0 + 2];
            o3 += a * W3s[k2 * NCc + c0 + 3];
        }
        *reinterpret_cast<float4*>(out + (size_t)r * NCc + c0) = make_float4(o0, o1, o2, o3);
    }
}

extern "C" void kernel_launch(void* const* d_in, const int* in_sizes, int n_in,
                              void* d_out, int out_size, void* d_ws, size_t ws_size,
                              hipStream_t stream) {
    const float* x   = (const float*)d_in[0];
    const float* W1  = (const float*)d_in[1];
    const float* b1  = (const float*)d_in[2];
    const float* W2  = (const float*)d_in[3];
    const float* b2  = (const float*)d_in[4];
    const float* Wf1 = (const float*)d_in[5];
    const float* bf1 = (const float*)d_in[6];
    const float* Wf2 = (const float*)d_in[7];
    const float* bf2 = (const float*)d_in[8];
    const float* Wf3 = (const float*)d_in[9];
    const float* bf3 = (const float*)d_in[10];
    const u32*   ei  = (const u32*)d_in[11];

    int N = in_sizes[0] / F_IN;
    int E = in_sizes[11] / 2;
    int B = (N + BUCKET - 1) >> BSH;
    if (B > BMAXB) return;           // fixed-size problem guard

    // workspace layout (16B-aligned segments)
    char* w = (char*)d_ws;
    u32* flags  = (u32*)w;   w += 64;
    float* dinv = (float*)w; w += (size_t)((N + 3) & ~3) * 4;
    u32* cnt    = (u32*)w;   w += (size_t)((N + 3) & ~3) * 4;
    u32* off    = (u32*)w;   w += (size_t)((N + 3) & ~3) * 4;
    float* h2p  = (float*)w; w += (size_t)N * H2c * 4;      // h2post [N][32]
    u32* perm   = (u32*)w;   w += ((size_t)E + 4096) * 4;
    u32* bbuf   = (u32*)w;   w += ((size_t)E + 4096) * 4;   // dead after k_csr
    u32* cntGB  = (u32*)w;   w += (size_t)GP * BMAXB * 4;
    u32* gbOff  = (u32*)w;   w += (size_t)GP * BMAXB * 4;
    u32* total  = (u32*)w;   w += (size_t)(BMAXB + 8) * 4;
    u32* bstartP= (u32*)w;   w += (size_t)(BMAXB + 8) * 4;
    // alias bbuf (dead after k_csr): h1h [N][16] fp16 + p2h [N][16] fp16 (N*16 u32 total)
    __half* h1h = (__half*)bbuf;
    __half* p2h = h1h + (size_t)N * H1c;

    k_detect<<<1, 256, 0, stream>>>(ei, flags);
    k_hist  <<<GP, 1024, 0, stream>>>(ei, E, B, flags, cntGB);
    k_scanG <<<B, GP, 0, stream>>>(cntGB, B, gbOff, total);
    k_scanB <<<1, 256, 0, stream>>>(total, B, bstartP);
    k_part  <<<GP, 1024, 0, stream>>>(ei, E, B, flags, gbOff, bstartP, bbuf);
    k_csr   <<<B, 1024, 0, stream>>>(bbuf, bstartP, total, N, cnt, off, dinv, perm);

    int nb16 = (N + 15) / 16;
    k_xw1<<<nb16, 256, 0, stream>>>(x, W1, dinv, h1h, N);
    int nb32 = (N + 31) / 32;
    k_agg1<<<nb32, 128, 0, stream>>>(h1h, perm, off, cnt, dinv, b1, p2h, N);
    k_agg2w2<<<nb32, 128, 0, stream>>>(p2h, perm, off, cnt, dinv, W2, b2, h2p, N);
    int nbN = (N + 255) / 256;
    k_mlp<<<nbN, 256, 0, stream>>>(h2p, Wf1, bf1, Wf2, bf2, Wf3, bf3, (float*)d_out, N);
}